// Round 1
// 1385.551 us; speedup vs baseline: 1.1706x; 1.1706x over previous
//
#include <hip/hip_runtime.h>
#include <stdint.h>

#define B_ 32
#define V_ 4096
#define H_ 1024

typedef __bf16 bf16x8 __attribute__((ext_vector_type(8)));
typedef float f32x4 __attribute__((ext_vector_type(4)));
typedef unsigned short u16x8 __attribute__((ext_vector_type(8)));

__device__ __forceinline__ unsigned short f2bf(float x) {
    unsigned int u = __float_as_uint(x);
    u += 0x7fffu + ((u >> 16) & 1u);
    return (unsigned short)(u >> 16);
}

// K1: Wk f32 [o][k] -> bf16 ushort [o][k]
__global__ __launch_bounds__(256) void wk_to_bf16(const float* __restrict__ wk,
                                                  unsigned short* __restrict__ out) {
    int i = (blockIdx.x * 256 + threadIdx.x) * 4;
    float4 f = *(const float4*)(wk + i);
    ushort4 u;
    u.x = f2bf(f.x); u.y = f2bf(f.y); u.z = f2bf(f.z); u.w = f2bf(f.w);
    *(ushort4*)(out + i) = u;
}

// K2: r[b][o] = bias[o] + sum_h query[b][h]*Wq[o][h]   (one wave per (b,o))
__global__ __launch_bounds__(256) void compute_r(const float* __restrict__ query,
                                                 const float* __restrict__ wq,
                                                 const float* __restrict__ bias,
                                                 float* __restrict__ r) {
    int gid = blockIdx.x * 4 + (threadIdx.x >> 6);
    int lane = threadIdx.x & 63;
    int b = gid & 31;
    int o = gid >> 5;
    const float4* q4 = (const float4*)(query + b * H_);
    const float4* w4 = (const float4*)(wq + (size_t)o * H_);
    float s = 0.f;
    #pragma unroll
    for (int i = 0; i < 4; ++i) {
        float4 q = q4[lane + i * 64];
        float4 w = w4[lane + i * 64];
        s += q.x * w.x + q.y * w.y + q.z * w.z + q.w * w.w;
    }
    #pragma unroll
    for (int m = 32; m >= 1; m >>= 1) s += __shfl_xor(s, m, 64);
    if (lane == 0) r[b * H_ + o] = s + bias[o];
}

// K3: fused  score[b,v] = sum_o Ws[o]*tanh( (key[b,v,:]·Wk[o,:]) + r[b,o] )
// 512 threads (8 waves), tile = 64 v-rows x full o=1024 (4 o-tiles of 256).
// A (key, bf16) resident in LDS, XOR-swizzled (no pad): key read from HBM once.
// B (Wk bf16) single LDS buffer, reg-staged double-buffer with loads issued
// TWO steps ahead; raw s_barrier (no implicit vmcnt(0) drain) keeps them in
// flight across barriers; compiler emits the counted vmcnt before ds_write.
__global__ __launch_bounds__(512) void score_kernel(const float* __restrict__ key,
                                                    const unsigned short* __restrict__ wkb,
                                                    const float* __restrict__ r,
                                                    const float* __restrict__ wsc,
                                                    float* __restrict__ score) {
    __shared__ unsigned short Alds[64 * 1024];   // swizzled: row*1024 + ((8*chunk) ^ ((row&15)<<3))
    __shared__ unsigned short Blds[256 * 40];    // 256 o-rows, BK=32 padded +8 (bank-even)

    int t = threadIdx.x;
    int b = blockIdx.x >> 6;
    int v0 = (blockIdx.x & 63) << 6;
    int lane = t & 63;
    int wid = t >> 6;
    int waveM = wid >> 2;   // 0..1  (32 v-rows each)
    int waveN = wid & 3;    // 0..3  (64 o-cols each)
    int l15 = lane & 15;
    int l4 = lane >> 4;     // 0..3

    // ---- B staging mapping: 2 threads per o-row, 32B each
    int o_r = t >> 1;
    int kh = t & 1;
    const unsigned short* wsrc = wkb + (size_t)o_r * H_ + kh * 16;
    unsigned short* bdst = Blds + o_r * 40 + kh * 16;

    // prime pipeline: chunks fs=0 and fs=1 (land during the A-stage below)
    uint4 g0a = *(const uint4*)(wsrc);
    uint4 g0b = *(const uint4*)(wsrc + 8);
    uint4 g1a = *(const uint4*)(wsrc + 32);
    uint4 g1b = *(const uint4*)(wsrc + 40);

    // ---- A stage: key[b, v0..v0+64, :] f32 -> bf16, swizzled LDS
    {
        int row = t >> 3;
        int j = t & 7;
        const float4* src = (const float4*)(key + ((size_t)(b * V_ + v0) + row) * H_);
        unsigned short* dst = Alds + row * 1024;
        int swz = (row & 15) << 3;
        #pragma unroll 8
        for (int it = 0; it < 16; ++it) {
            int c = j + it * 8;                 // 8-bf16 chunk index 0..127
            float4 f0 = src[2 * c];
            float4 f1 = src[2 * c + 1];
            u16x8 u;
            u[0] = f2bf(f0.x); u[1] = f2bf(f0.y); u[2] = f2bf(f0.z); u[3] = f2bf(f0.w);
            u[4] = f2bf(f1.x); u[5] = f2bf(f1.y); u[6] = f2bf(f1.z); u[7] = f2bf(f1.w);
            *(u16x8*)(dst + ((c * 8) ^ swz)) = u;
        }
    }

    const unsigned short* aBase0 = Alds + (waveM * 32 + l15) * 1024;
    const unsigned short* aBase1 = aBase0 + 16 * 1024;
    const unsigned short* bBase = Blds + (waveN * 64 + l15) * 40 + l4 * 8;
    int aswz = l15 << 3;

    float sAcc[2][4];
    #pragma unroll
    for (int mi = 0; mi < 2; ++mi)
        #pragma unroll
        for (int rg = 0; rg < 4; ++rg) sAcc[mi][rg] = 0.f;

    for (int ot = 0; ot < 4; ++ot) {
        int obase = ot << 8;
        f32x4 acc[2][4];
        #pragma unroll
        for (int mi = 0; mi < 2; ++mi)
            #pragma unroll
            for (int nj = 0; nj < 4; ++nj)
                acc[mi][nj] = (f32x4){0.f, 0.f, 0.f, 0.f};
        float rv[4], wv[4];
        #pragma unroll
        for (int nj = 0; nj < 4; ++nj) {
            int o = obase + waveN * 64 + nj * 16 + l15;
            rv[nj] = r[b * H_ + o];
            wv[nj] = wsc[o];
        }

        for (int kc = 0; kc < 32; kc += 2) {
            // ---------- even step: consume g0 (chunk ot*32+kc), prefetch +2
            __builtin_amdgcn_s_barrier();                 // all waves done reading prev B
            asm volatile("" ::: "memory");
            *(uint4*)(bdst) = g0a;                        // compiler: counted vmcnt(2)
            *(uint4*)(bdst + 8) = g0b;
            {
                int fs = ot * 32 + kc + 2;                // may overrun into r/score ws: harmless
                const unsigned short* p = wsrc + (fs >> 5) * (256 * H_) + (fs & 31) * 32;
                g0a = *(const uint4*)(p);
                g0b = *(const uint4*)(p + 8);
            }
            asm volatile("s_waitcnt lgkmcnt(0)" ::: "memory");  // my ds_writes retired
            __builtin_amdgcn_s_barrier();                 // B chunk visible; NO vmcnt drain
            asm volatile("" ::: "memory");
            {
                int aoff = (kc * 32 + l4 * 8) ^ aswz;
                bf16x8 af0 = *(const bf16x8*)(aBase0 + aoff);
                bf16x8 af1 = *(const bf16x8*)(aBase1 + aoff);
                #pragma unroll
                for (int nj = 0; nj < 4; ++nj) {
                    bf16x8 bv = *(const bf16x8*)(bBase + nj * (16 * 40));
                    acc[0][nj] = __builtin_amdgcn_mfma_f32_16x16x32_bf16(af0, bv, acc[0][nj], 0, 0, 0);
                    acc[1][nj] = __builtin_amdgcn_mfma_f32_16x16x32_bf16(af1, bv, acc[1][nj], 0, 0, 0);
                }
            }
            // ---------- odd step: consume g1 (chunk ot*32+kc+1), prefetch +2
            __builtin_amdgcn_s_barrier();
            asm volatile("" ::: "memory");
            *(uint4*)(bdst) = g1a;
            *(uint4*)(bdst + 8) = g1b;
            {
                int fs = ot * 32 + kc + 3;
                const unsigned short* p = wsrc + (fs >> 5) * (256 * H_) + (fs & 31) * 32;
                g1a = *(const uint4*)(p);
                g1b = *(const uint4*)(p + 8);
            }
            asm volatile("s_waitcnt lgkmcnt(0)" ::: "memory");
            __builtin_amdgcn_s_barrier();
            asm volatile("" ::: "memory");
            {
                int aoff = ((kc + 1) * 32 + l4 * 8) ^ aswz;
                bf16x8 af0 = *(const bf16x8*)(aBase0 + aoff);
                bf16x8 af1 = *(const bf16x8*)(aBase1 + aoff);
                #pragma unroll
                for (int nj = 0; nj < 4; ++nj) {
                    bf16x8 bv = *(const bf16x8*)(bBase + nj * (16 * 40));
                    acc[0][nj] = __builtin_amdgcn_mfma_f32_16x16x32_bf16(af0, bv, acc[0][nj], 0, 0, 0);
                    acc[1][nj] = __builtin_amdgcn_mfma_f32_16x16x32_bf16(af1, bv, acc[1][nj], 0, 0, 0);
                }
            }
        }

        // per-o-tile epilogue: tanh + Ws weighting, accumulated lane-locally
        // C/D layout: col(o)=l15, row(v)= l4*4+rg within each 16x16 fragment
        #pragma unroll
        for (int mi = 0; mi < 2; ++mi)
            #pragma unroll
            for (int rg = 0; rg < 4; ++rg) {
                float s = 0.f;
                #pragma unroll
                for (int nj = 0; nj < 4; ++nj) {
                    float x = acc[mi][nj][rg] + rv[nj];
                    float e = __expf(2.f * x);
                    float th = 1.f - 2.f / (e + 1.f);   // tanh, inf-safe
                    s += th * wv[nj];
                }
                sAcc[mi][rg] += s;
            }
    }

    // final reduction: 16-lane shfl over o-columns, combine 4 N-waves via LDS atomics
    __syncthreads();                       // full drain (incl. dead tail prefetch); A reads done
    float* sb = (float*)Alds;              // alias score buffer into Alds
    if (t < 64) sb[t] = 0.f;
    __syncthreads();
    #pragma unroll
    for (int mi = 0; mi < 2; ++mi)
        #pragma unroll
        for (int rg = 0; rg < 4; ++rg) {
            float s = sAcc[mi][rg];
            s += __shfl_xor(s, 1, 64);
            s += __shfl_xor(s, 2, 64);
            s += __shfl_xor(s, 4, 64);
            s += __shfl_xor(s, 8, 64);
            if (l15 == 0) atomicAdd(&sb[waveM * 32 + mi * 16 + l4 * 4 + rg], s);
        }
    __syncthreads();
    if (t < 64) score[b * V_ + v0 + t] = sb[t];
}

// K4: softmax over V per b  (bs dropped: softmax shift-invariant)
__global__ __launch_bounds__(256) void softmax_kernel(const float* __restrict__ score,
                                                      float* __restrict__ attn) {
    int b = blockIdx.x, t = threadIdx.x;
    __shared__ float red[8];
    const float* s = score + b * V_;
    float v[16];
    float mx = -1e30f;
    #pragma unroll
    for (int i = 0; i < 16; ++i) { v[i] = s[t + i * 256]; mx = fmaxf(mx, v[i]); }
    #pragma unroll
    for (int m = 32; m >= 1; m >>= 1) mx = fmaxf(mx, __shfl_xor(mx, m, 64));
    if ((t & 63) == 0) red[t >> 6] = mx;
    __syncthreads();
    mx = fmaxf(fmaxf(red[0], red[1]), fmaxf(red[2], red[3]));
    float sum = 0.f;
    #pragma unroll
    for (int i = 0; i < 16; ++i) { v[i] = __expf(v[i] - mx); sum += v[i]; }
    #pragma unroll
    for (int m = 32; m >= 1; m >>= 1) sum += __shfl_xor(sum, m, 64);
    if ((t & 63) == 0) red[4 + (t >> 6)] = sum;
    __syncthreads();
    float inv = 1.f / (red[4] + red[5] + red[6] + red[7]);
    float* a = attn + b * V_;
    #pragma unroll
    for (int i = 0; i < 16; ++i) a[t + i * 256] = v[i] * inv;
}

// K5: context[b,h] = sum_v attn[b,v]*value[b,v,h]   (BW-bound stream)
__global__ __launch_bounds__(256) void context_kernel(const float* __restrict__ value,
                                                      const float* __restrict__ attn,
                                                      float* __restrict__ ctx) {
    int b = blockIdx.x, hc = blockIdx.y, vc = blockIdx.z, t = threadIdx.x;
    __shared__ float a[512];
    int vb = vc * 512;
    a[t] = attn[b * V_ + vb + t];
    a[t + 256] = attn[b * V_ + vb + t + 256];
    __syncthreads();
    int h = hc * 256 + t;
    const float* vp = value + ((size_t)(b * V_ + vb)) * H_ + h;
    float acc = 0.f;
    #pragma unroll 8
    for (int i = 0; i < 512; ++i) acc += a[i] * vp[(size_t)i * H_];
    atomicAdd(&ctx[b * H_ + h], acc);
}

extern "C" void kernel_launch(void* const* d_in, const int* in_sizes, int n_in,
                              void* d_out, int out_size, void* d_ws, size_t ws_size,
                              hipStream_t stream) {
    const float* query = (const float*)d_in[0];
    const float* key   = (const float*)d_in[1];
    const float* value = (const float*)d_in[2];
    const float* Wq    = (const float*)d_in[3];
    const float* Wk    = (const float*)d_in[4];
    const float* bias  = (const float*)d_in[5];
    const float* Wsv   = (const float*)d_in[6];
    // d_in[7] = bs : constant shift, cancels in softmax; context unaffected.

    unsigned short* wkb = (unsigned short*)d_ws;                        // 2 MB
    float* r     = (float*)((char*)d_ws + (2u << 20));                  // 128 KB
    float* score = (float*)((char*)d_ws + (2u << 20) + (128u << 10));   // 512 KB

    float* ctx  = (float*)d_out;             // 32*1024
    float* attn = (float*)d_out + 32 * 1024; // 32*4096

    hipMemsetAsync(ctx, 0, 32 * 1024 * sizeof(float), stream);
    wk_to_bf16<<<1024, 256, 0, stream>>>(Wk, wkb);
    compute_r<<<8192, 256, 0, stream>>>(query, Wq, bias, r);
    score_kernel<<<2048, 512, 0, stream>>>(key, wkb, r, Wsv, score);
    softmax_kernel<<<32, 256, 0, stream>>>(score, attn);
    context_kernel<<<dim3(32, 4, 8), 256, 0, stream>>>(value, attn, ctx);
}